// Round 16
// baseline (107.766 us; speedup 1.0000x reference)
//
#include <hip/hip_runtime.h>
#include <hip/hip_bf16.h>

// B=64, I=64, O=64, G=4096, X=4, RHO=1
#define BB 64
#define II 64
#define OO 64
#define GG 4096
#define KP 64            // g per phase
#define NPH 32           // phases (2048 g per block / 64)
#define NSL 512          // partial slices (64x64 bf16) = 4 MB

typedef short bf16x8 __attribute__((ext_vector_type(8)));
typedef float f32x4  __attribute__((ext_vector_type(4)));
typedef unsigned short u16x4 __attribute__((ext_vector_type(4)));

static __device__ __forceinline__ short f2bf(float f) {
    __hip_bfloat16 h = __float2bfloat16(f);
    return __builtin_bit_cast(short, h);
}
static __device__ __forceinline__ unsigned short f2bfu(float f) {
    __hip_bfloat16 h = __float2bfloat16(f);
    return __builtin_bit_cast(unsigned short, h);
}
static __device__ __forceinline__ float bfu2f(unsigned short u) {
    unsigned int v = (unsigned int)u << 16;
    return __builtin_bit_cast(float, v);
}

// ---------------------------------------------------------------------------
// r16: 3-BLOCKS-PER-CU variant of the r15 pipeline. Block (i, oc quarter,
// gch half) owns 16 o-rows x 2048 g; 32 phases of KP=64; per-row global
// streams are 32 KB sequential (1-KB extents, r15's win preserved). LDS
// 41 KB (Wst 2x16 + As 8 + Gs 1) -> 3 blocks/CU = 24 waves/CU: three
// independent barrier domains interleave their staging/consume windows,
// plugging the ~35% HBM duty-cycle hole measured on the 2-block r15 shape.
//
// Proven pieces kept verbatim: gload_lds raw-f32 staging (r8/r12: nothing
// for the allocator to sink), counted s_waitcnt vmcnt(2) mid-loop (never
// 0), single-As with register-carry write-after-end-barrier, store-side
// source-unit swizzle qs = ((row&3)<<1)|((u>>3)&1) with matching read-side
// qp (involution verified in r15), phase rotation (r10).
//
// Per phase per wave: stage 2 rows (rr = q*8+wv, q=0..1) + 1 G load;
// consume: wave owns tiles (mt=wv&3, nt=2*(wv>>2)+{0,1}); per kk: 1 af
// b128 + 2x8 b32+cvt bb + 2 MFMA. acc = 2 x f32x4 = 8 VGPR.
// ---------------------------------------------------------------------------
__global__ __launch_bounds__(512, 4)
void kan_main(const float* __restrict__ xg, const float* __restrict__ grd,
              const float* __restrict__ wts, unsigned short* __restrict__ dst,
              float* __restrict__ fdst, int atomic_mode)
{
    __shared__ __align__(16) float          Wst[2][16 * 256]; // 16KB x2
    __shared__ __align__(16) unsigned short As [BB * KP];     //  8KB
    __shared__ __align__(16) float4         Gs [KP];          //  1KB

    const int i   = blockIdx.x;          // 0..63
    const int oc  = blockIdx.y;          // 0..3   o-quarter (16 rows)
    const int gch = blockIdx.z;          // 0..1   g-half (2048 g)
    const int s   = (i + 8 * oc + 16 * gch) & (NPH - 1);

    const int t    = threadIdx.x;
    const int lane = t & 63;
    const int wv   = t >> 6;             // 0..7

    // rbf map: thread computes 8 g for one b-row
    const int brow = t >> 3;
    const int oct  = t & 7;
    const float4 xv = reinterpret_cast<const float4*>(xg)[brow * II + i];

    // weights: 2 rows per wave (rr = q*8+wv), 1 KB contiguous per phase
    const float4* w4 = reinterpret_cast<const float4*>(wts)
        + ((size_t)i * OO + oc * 16) * GG + (size_t)gch * 2048;
    const float4* g4 = reinterpret_cast<const float4*>(grd) + gch * 2048;
    const int qs_hi = (lane >> 3) & 1;

    // ---- prologue ----
    __builtin_amdgcn_global_load_lds(g4 + s * KP + lane, (char*)(&Gs[0]),
                                     16, 0, 0);
    #pragma unroll
    for (int q = 0; q < 2; ++q) {
        const int rr = q * 8 + wv;
        const int qs = ((rr & 3) << 1) | qs_hi;
        __builtin_amdgcn_global_load_lds(
            w4 + (size_t)rr * GG + s * KP + (lane ^ qs),
            (char*)(&Wst[0][0]) + rr * 1024, 16, 0, 0);
    }
    asm volatile("s_waitcnt vmcnt(2)" ::: "memory");   // xv + G(s) landed

    {   // rbf(s) -> As (no readers yet)
        bf16x8 pa;
        #pragma unroll
        for (int e = 0; e < 8; ++e) {
            const float4 g = Gs[oct * 8 + e];
            const float d0 = xv.x - g.x, d1 = xv.y - g.y,
                        d2 = xv.z - g.z, d3 = xv.w - g.w;
            pa[e] = f2bf(__expf(-(d0*d0 + d1*d1 + d2*d2 + d3*d3)));
        }
        *reinterpret_cast<bf16x8*>(
            &As[brow * KP + ((oct * 8) ^ ((brow & 7) << 3))]) = pa;
    }
    asm volatile("s_waitcnt lgkmcnt(0)\n\ts_barrier" ::: "memory");
    __builtin_amdgcn_global_load_lds(g4 + ((s + 1) & (NPH - 1)) * KP + lane,
                                     (char*)(&Gs[0]), 16, 0, 0);

    f32x4 acc[2];
    acc[0] = {0.f, 0.f, 0.f, 0.f};
    acc[1] = {0.f, 0.f, 0.f, 0.f};

    const int lg   = lane >> 4;
    const int r16  = lane & 15;
    const int mt   = wv & 3;               // wave's m-tile
    const int ntg  = wv >> 2;              // n-tile group (2 tiles)
    const int bx   = r16 & 3;

    for (int p = 0; p < NPH; ++p) {
        const int b  = p & 1;
        const int np = (p + 1 + s) & (NPH - 1);

        // 1. issue W(np) -> Wst[b^1]
        if (p + 1 < NPH) {
            #pragma unroll
            for (int q = 0; q < 2; ++q) {
                const int rr = q * 8 + wv;
                const int qs = ((rr & 3) << 1) | qs_hi;
                __builtin_amdgcn_global_load_lds(
                    w4 + (size_t)rr * GG + np * KP + (lane ^ qs),
                    (char*)(&Wst[b ^ 1][0]) + rr * 1024, 16, 0, 0);
            }
        }

        // 2. counted wait: retires {W(cp) x2, G(np)}; W(np) stays in flight
        if (p + 1 < NPH)
            asm volatile("s_waitcnt vmcnt(2)" ::: "memory");
        else
            asm volatile("s_waitcnt vmcnt(0)" ::: "memory");

        // 3. rbf(np) -> regs (Gs holds chunk np)
        bf16x8 pa;
        if (p + 1 < NPH) {
            #pragma unroll
            for (int e = 0; e < 8; ++e) {
                const float4 g = Gs[oct * 8 + e];
                const float d0 = xv.x - g.x, d1 = xv.y - g.y,
                            d2 = xv.z - g.z, d3 = xv.w - g.w;
                pa[e] = f2bf(__expf(-(d0*d0 + d1*d1 + d2*d2 + d3*d3)));
            }
        }

        // 4. mid barrier: Wst[b] + As writes visible block-wide
        asm volatile("s_waitcnt lgkmcnt(0)\n\ts_barrier" ::: "memory");

        // 5. consume
        #pragma unroll
        for (int kk = 0; kk < 2; ++kk) {
            const int rA = mt * 16 + r16;
            const bf16x8 af = *reinterpret_cast<const bf16x8*>(
                &As[rA * KP + ((kk * 32 + lg * 8) ^ ((rA & 7) << 3))]);
            #pragma unroll
            for (int nn = 0; nn < 2; ++nn) {
                const int nt   = ntg * 2 + nn;
                const int orow = nt * 4 + (r16 >> 2);    // 0..15
                const int qp   = ((orow & 3) << 1) | (lg & 1);
                bf16x8 bb;
                #pragma unroll
                for (int e = 0; e < 8; ++e) {
                    const int g = kk * 32 + lg * 8 + e;
                    bb[e] = f2bf(Wst[b][orow * 256 + ((g ^ qp) << 2) + bx]);
                }
                acc[nn] = __builtin_amdgcn_mfma_f32_16x16x32_bf16(
                    af, bb, acc[nn], 0, 0, 0);
            }
        }

        // 6. end barrier: all LDS reads of this phase retired
        asm volatile("s_waitcnt lgkmcnt(0)\n\ts_barrier" ::: "memory");

        // 7. write As <- rbf(np) (safe: all As reads drained)
        if (p + 1 < NPH) {
            *reinterpret_cast<bf16x8*>(
                &As[brow * KP + ((oct * 8) ^ ((brow & 7) << 3))]) = pa;
        }
        // 8. issue G(np2) -> Gs (safe: all Gs reads drained)
        if (p + 2 < NPH) {
            __builtin_amdgcn_global_load_lds(
                g4 + ((p + 2 + s) & (NPH - 1)) * KP + lane,
                (char*)(&Gs[0]), 16, 0, 0);
        }
    }

    // ---- epilogue: C/D col=lane&15 -> n, row=(lane>>4)*4+r -> m ----
    const int mb = mt * 16 + ((lane >> 4) << 2);
    if (!atomic_mode) {
        unsigned short* pd = dst
            + (size_t)((i * 4 + oc) * 2 + gch) * (BB * 64);
        #pragma unroll
        for (int nn = 0; nn < 2; ++nn) {
            const int n = (ntg * 2 + nn) * 16 + r16;
            #pragma unroll
            for (int r = 0; r < 4; ++r)
                pd[(mb + r) * 64 + n] = f2bfu(acc[nn][r]);
        }
    } else {
        #pragma unroll
        for (int nn = 0; nn < 2; ++nn) {
            const int n = oc * 64 + (ntg * 2 + nn) * 16 + r16;
            #pragma unroll
            for (int r = 0; r < 4; ++r)
                atomicAdd(&fdst[(mb + r) * 256 + n], acc[nn][r]);
        }
    }
}

// ---------------------------------------------------------------------------
// Fused tail: 256 blocks x 16 (b,o) pairs. oc = o>>4; sum the 128 slices
// (i x gch) at column (o&15)*4+x; 16 threads/pair x 8 slices -> LDS reduce
// -> 16 finishers do the 64-i SiLU/Cayley (Cl(2,0)) + bias.
// Slice sl = (i*4+oc)*2+gch, layout [64 b][64 n] bf16.
// ---------------------------------------------------------------------------
__global__ __launch_bounds__(256)
void kan_tail(const unsigned short* __restrict__ part,
              const float* __restrict__ xg,
              const float* __restrict__ sw,
              const float* __restrict__ sb,
              float* __restrict__ out)
{
    __shared__ float4 sums[16][16];

    const int t     = threadIdx.x;
    const int bid   = blockIdx.x;            // 0..255
    const int pairL = t & 15;
    const int rgrp  = t >> 4;
    const int pairG = bid * 16 + pairL;
    const int b     = pairG >> 6, o = pairG & 63;
    const int oc    = o >> 4;
    const int ncol  = (o & 15) * 4;

    float4 s4 = make_float4(0.f, 0.f, 0.f, 0.f);
    #pragma unroll 4
    for (int m = 0; m < 8; ++m) {
        const int idx = rgrp * 8 + m;        // (i, gch), 0..127
        const int ii  = idx >> 1, gg = idx & 1;
        const size_t sl = (size_t)((ii * 4 + oc) * 2 + gg);
        const u16x4 v = *reinterpret_cast<const u16x4*>(
            part + sl * (BB * 64) + b * 64 + ncol);
        s4.x += bfu2f(v[0]); s4.y += bfu2f(v[1]);
        s4.z += bfu2f(v[2]); s4.w += bfu2f(v[3]);
    }
    sums[pairL][rgrp] = s4;
    __syncthreads();

    if (t < 16) {
        const int pg = bid * 16 + t;
        const int bb = pg >> 6, oo = pg & 63;

        float o0 = 0.f, o1 = 0.f, o2 = 0.f, o3 = 0.f;
        #pragma unroll
        for (int r = 0; r < 16; ++r) {
            const float4 v = sums[t][r];
            o0 += v.x; o1 += v.y; o2 += v.z; o3 += v.w;
        }

        const float4* xg4 = reinterpret_cast<const float4*>(xg);
        const float4* sw4 = reinterpret_cast<const float4*>(sw);
        const float4* sb4 = reinterpret_cast<const float4*>(sb);
        #pragma unroll 4
        for (int i = 0; i < II; ++i) {
            const float4 xvv = xg4[bb * II + i];
            const float4 swv = sw4[i * OO + oo];
            const float4 sbv = sb4[i * OO + oo];
            const float s0 = xvv.x / (1.f + __expf(-xvv.x));
            const float s1 = xvv.y / (1.f + __expf(-xvv.y));
            const float s2 = xvv.z / (1.f + __expf(-xvv.z));
            const float s3 = xvv.w / (1.f + __expf(-xvv.w));
            o0 += swv.x * s0 + swv.y * s1 + swv.z * s2 - swv.w * s3 + sbv.x;
            o1 += swv.x * s1 + swv.y * s0 - swv.z * s3 + swv.w * s2 + sbv.y;
            o2 += swv.x * s2 + swv.y * s3 + swv.z * s0 - swv.w * s1 + sbv.z;
            o3 += swv.x * s3 + swv.y * s2 - swv.z * s1 + swv.w * s0 + sbv.w;
        }
        reinterpret_cast<float4*>(out)[pg] = make_float4(o0, o1, o2, o3);
    }
}

// ---------------------------------------------------------------------------
// Fallback-only final kernel (atomic path): main sums already in out
// ---------------------------------------------------------------------------
__global__ void kan_out(const float* __restrict__ xg,
                        const float* __restrict__ sw,
                        const float* __restrict__ sb,
                        float* __restrict__ out)
{
    const int t = blockIdx.x * 256 + threadIdx.x;    // (b,o)
    const int b = t >> 6, o = t & 63;

    const float4 v = reinterpret_cast<const float4*>(out)[t];
    float o0 = v.x, o1 = v.y, o2 = v.z, o3 = v.w;

    const float4* xg4 = reinterpret_cast<const float4*>(xg);
    const float4* sw4 = reinterpret_cast<const float4*>(sw);
    const float4* sb4 = reinterpret_cast<const float4*>(sb);
    #pragma unroll 4
    for (int i = 0; i < II; ++i) {
        const float4 xvv = xg4[b * II + i];
        const float4 swv = sw4[i * OO + o];
        const float4 sbv = sb4[i * OO + o];
        const float s0 = xvv.x / (1.f + __expf(-xvv.x));
        const float s1 = xvv.y / (1.f + __expf(-xvv.y));
        const float s2 = xvv.z / (1.f + __expf(-xvv.z));
        const float s3 = xvv.w / (1.f + __expf(-xvv.w));
        o0 += swv.x * s0 + swv.y * s1 + swv.z * s2 - swv.w * s3 + sbv.x;
        o1 += swv.x * s1 + swv.y * s0 - swv.z * s3 + swv.w * s2 + sbv.y;
        o2 += swv.x * s2 + swv.y * s3 + swv.z * s0 - swv.w * s1 + sbv.z;
        o3 += swv.x * s3 + swv.y * s2 - swv.z * s1 + swv.w * s0 + sbv.w;
    }
    reinterpret_cast<float4*>(out)[t] = make_float4(o0, o1, o2, o3);
}

// ---------------------------------------------------------------------------
extern "C" void kernel_launch(void* const* d_in, const int* in_sizes, int n_in,
                              void* d_out, int out_size, void* d_ws, size_t ws_size,
                              hipStream_t stream)
{
    const float* x   = (const float*)d_in[0];
    const float* grd = (const float*)d_in[1];
    const float* w   = (const float*)d_in[2];
    const float* sw  = (const float*)d_in[3];
    const float* sb  = (const float*)d_in[4];
    float* out = (float*)d_out;

    const size_t need = (size_t)NSL * (BB * 64) * 2;   // 4 MB

    if (ws_size >= need) {
        unsigned short* ws = (unsigned short*)d_ws;
        kan_main<<<dim3(64, 4, 2), 512, 0, stream>>>(x, grd, w, ws, nullptr, 0);
        kan_tail<<<256, 256, 0, stream>>>(ws, x, sw, sb, out);
    } else {
        hipMemsetAsync(d_out, 0, (size_t)out_size * sizeof(float), stream);
        kan_main<<<dim3(64, 4, 2), 512, 0, stream>>>(x, grd, w, nullptr, out, 1);
        kan_out<<<16, 256, 0, stream>>>(x, sw, sb, out);
    }
}

// Round 17
// 70.279 us; speedup vs baseline: 1.5334x; 1.5334x over previous
//
#include <hip/hip_runtime.h>
#include <hip/hip_bf16.h>

// B=64, I=64, O=64, G=4096, X=4, RHO=1
#define BB 64
#define II 64
#define OO 64
#define GG 4096
#define KP 64            // g per phase
#define NPH 16           // phases (1024 g per block / 64)
#define NSL 512          // partial slices (bf16), 8 MB

typedef short bf16x8 __attribute__((ext_vector_type(8)));
typedef float f32x4  __attribute__((ext_vector_type(4)));
typedef unsigned short u16x4 __attribute__((ext_vector_type(4)));

static __device__ __forceinline__ short f2bf(float f) {
    __hip_bfloat16 h = __float2bfloat16(f);
    return __builtin_bit_cast(short, h);
}
static __device__ __forceinline__ unsigned short f2bfu(float f) {
    __hip_bfloat16 h = __float2bfloat16(f);
    return __builtin_bit_cast(unsigned short, h);
}
static __device__ __forceinline__ float bfu2f(unsigned short u) {
    unsigned int v = (unsigned int)u << 16;
    return __builtin_bit_cast(float, v);
}

// ---------------------------------------------------------------------------
// r17 = r15 RESTORED VERBATIM (best: 70.6 us). r16's 3-blk/CU split
// regressed 53% (fewer in-flight loads/wave + 2x barrier count) -> the
// 2-blk/CU, 16-phase, 4-loads-in-flight shape is the empirical optimum.
//
// SEQUENTIAL-STREAM tiling: block (i, oc half, gch quarter) owns 32 o-rows
// x 1024 g; 16 phases of KP=64. Each wave stages 4 rows/phase as ONE 1-KB
// contiguous gload_lds per row; consecutive phases read consecutive 1-KB
// chunks -> 16-KB sequential per-row streams. Counted vmcnt(4) mid-loop
// (never 0); grid staged via gload_lds into a rolling 1-KB Gs INSIDE the
// counted stream. As single-buffered: rbf(np) computed to regs during
// phase p, written to As after the end-barrier (race-free by lgkmcnt(0)+
// barrier). Wst store swizzle qs = ((row&3)<<1)|((u>>3)&1) (involution),
// consume-side b32 reads 2-way. As swizzle: unit ^= (row&7). Phase
// rotation s decorrelates DRAM channel bits across blocks (r10 win).
// LDS 64+8+1 = 73 KB -> 2 blocks/CU.
// ---------------------------------------------------------------------------
__global__ __launch_bounds__(512, 4)
void kan_main(const float* __restrict__ xg, const float* __restrict__ grd,
              const float* __restrict__ wts, unsigned short* __restrict__ dst,
              float* __restrict__ fdst, int atomic_mode)
{
    __shared__ __align__(16) float          Wst[2][32 * 256]; // 32KB x2
    __shared__ __align__(16) unsigned short As [BB * KP];     //  8KB
    __shared__ __align__(16) float4         Gs [KP];          //  1KB

    const int i   = blockIdx.x;          // 0..63
    const int oc  = blockIdx.y;          // 0..1   o-half
    const int gch = blockIdx.z;          // 0..3   g-quarter
    const int s   = (i + 4 * gch + 8 * oc) & (NPH - 1);

    const int t    = threadIdx.x;
    const int lane = t & 63;
    const int wv   = t >> 6;             // 0..7

    // rbf map: thread computes 8 g for one b-row
    const int brow = t >> 3;
    const int oct  = t & 7;
    const float4 xv = reinterpret_cast<const float4*>(xg)[brow * II + i];

    // weights: 4 rows per wave (rr = q*8+wv), contiguous 1 KB per phase
    const float4* w4 = reinterpret_cast<const float4*>(wts)
        + ((size_t)i * OO + oc * 32) * GG + (size_t)gch * 1024;
    const float4* g4 = reinterpret_cast<const float4*>(grd) + gch * 1024;
    const int qs_hi = (lane >> 3) & 1;   // store-swizzle bit from slot

    // ---- prologue ----
    __builtin_amdgcn_global_load_lds(g4 + s * KP + lane, (char*)(&Gs[0]),
                                     16, 0, 0);
    #pragma unroll
    for (int q = 0; q < 4; ++q) {
        const int rr = q * 8 + wv;
        const int qs = ((rr & 3) << 1) | qs_hi;
        __builtin_amdgcn_global_load_lds(
            w4 + (size_t)rr * GG + s * KP + (lane ^ qs),
            (char*)(&Wst[0][0]) + rr * 1024, 16, 0, 0);
    }
    asm volatile("s_waitcnt vmcnt(4)" ::: "memory");   // xv + G(s) landed

    {   // rbf(s) -> As (no readers yet)
        bf16x8 pa;
        #pragma unroll
        for (int e = 0; e < 8; ++e) {
            const float4 g = Gs[oct * 8 + e];
            const float d0 = xv.x - g.x, d1 = xv.y - g.y,
                        d2 = xv.z - g.z, d3 = xv.w - g.w;
            pa[e] = f2bf(__expf(-(d0*d0 + d1*d1 + d2*d2 + d3*d3)));
        }
        *reinterpret_cast<bf16x8*>(
            &As[brow * KP + ((oct * 8) ^ ((brow & 7) << 3))]) = pa;
    }
    asm volatile("s_waitcnt lgkmcnt(0)\n\ts_barrier" ::: "memory");
    // Gs free -> issue G(s+1)
    __builtin_amdgcn_global_load_lds(g4 + ((s + 1) & (NPH - 1)) * KP + lane,
                                     (char*)(&Gs[0]), 16, 0, 0);

    f32x4 acc[4];
    #pragma unroll
    for (int mt = 0; mt < 4; ++mt) acc[mt] = {0.f, 0.f, 0.f, 0.f};

    const int lg   = lane >> 4;
    const int r16  = lane & 15;
    const int orow = wv * 4 + (r16 >> 2);  // wave's o-rows (nt = wv)
    const int bx   = r16 & 3;

    for (int p = 0; p < NPH; ++p) {
        const int b  = p & 1;
        const int np = (p + 1 + s) & (NPH - 1);

        // 1. issue W(np) -> Wst[b^1]
        if (p + 1 < NPH) {
            #pragma unroll
            for (int q = 0; q < 4; ++q) {
                const int rr = q * 8 + wv;
                const int qs = ((rr & 3) << 1) | qs_hi;
                __builtin_amdgcn_global_load_lds(
                    w4 + (size_t)rr * GG + np * KP + (lane ^ qs),
                    (char*)(&Wst[b ^ 1][0]) + rr * 1024, 16, 0, 0);
            }
        }

        // 2. counted wait: retires {W(cp) x4, G(np)}; W(np) stays in flight
        if (p + 1 < NPH)
            asm volatile("s_waitcnt vmcnt(4)" ::: "memory");
        else
            asm volatile("s_waitcnt vmcnt(0)" ::: "memory");

        // 3. rbf(np) -> regs (Gs holds chunk np)
        bf16x8 pa;
        if (p + 1 < NPH) {
            #pragma unroll
            for (int e = 0; e < 8; ++e) {
                const float4 g = Gs[oct * 8 + e];
                const float d0 = xv.x - g.x, d1 = xv.y - g.y,
                            d2 = xv.z - g.z, d3 = xv.w - g.w;
                pa[e] = f2bf(__expf(-(d0*d0 + d1*d1 + d2*d2 + d3*d3)));
            }
        }

        // 4. mid barrier: Wst[b] (all waves) + As(cp) writes visible
        asm volatile("s_waitcnt lgkmcnt(0)\n\ts_barrier" ::: "memory");

        // 5. consume: per kk build bb once, af x4 mt, 8 MFMA
        #pragma unroll
        for (int kk = 0; kk < 2; ++kk) {
            bf16x8 bb;
            #pragma unroll
            for (int e = 0; e < 8; ++e) {
                const int g  = kk * 32 + lg * 8 + e;
                const int qp = ((orow & 3) << 1) | (lg & 1);
                bb[e] = f2bf(Wst[b][orow * 256 + ((g ^ qp) << 2) + bx]);
            }
            #pragma unroll
            for (int mt = 0; mt < 4; ++mt) {
                const int rA = mt * 16 + r16;
                const bf16x8 af = *reinterpret_cast<const bf16x8*>(
                    &As[rA * KP + ((kk * 32 + lg * 8) ^ ((rA & 7) << 3))]);
                acc[mt] = __builtin_amdgcn_mfma_f32_16x16x32_bf16(
                    af, bb, acc[mt], 0, 0, 0);
            }
        }

        // 6. end barrier: all As/Wst/Gs reads of this phase retired
        asm volatile("s_waitcnt lgkmcnt(0)\n\ts_barrier" ::: "memory");

        // 7. write As <- rbf(np) (safe: all As reads drained)
        if (p + 1 < NPH) {
            *reinterpret_cast<bf16x8*>(
                &As[brow * KP + ((oct * 8) ^ ((brow & 7) << 3))]) = pa;
        }
        // 8. issue G(np2) -> Gs (safe: all Gs reads drained)
        if (p + 2 < NPH) {
            __builtin_amdgcn_global_load_lds(
                g4 + ((p + 2 + s) & (NPH - 1)) * KP + lane,
                (char*)(&Gs[0]), 16, 0, 0);
        }
    }

    // ---- epilogue: C/D col=lane&15 -> n-local, row=(lane>>4)*4+r -> m ----
    const int nloc = wv * 16 + r16;          // 0..127
    const int mb   = ((lane >> 4) << 2);
    if (!atomic_mode) {
        unsigned short* pd = dst
            + (size_t)((i * 2 + oc) * 4 + gch) * (BB * 128);
        #pragma unroll
        for (int mt = 0; mt < 4; ++mt)
            #pragma unroll
            for (int r = 0; r < 4; ++r)
                pd[(mt * 16 + mb + r) * 128 + nloc] = f2bfu(acc[mt][r]);
    } else {
        #pragma unroll
        for (int mt = 0; mt < 4; ++mt)
            #pragma unroll
            for (int r = 0; r < 4; ++r)
                atomicAdd(&fdst[(mt * 16 + mb + r) * 256 + oc * 128 + nloc],
                          acc[mt][r]);
    }
}

// ---------------------------------------------------------------------------
// Fused tail: 256 blocks. Pair (b,o): sum 256 slices (i x gch for oc=o>>5),
// 16 threads/pair x 16 slices each -> LDS reduce -> 16 finisher threads do
// the 64-i SiLU/Cayley (Cl(2,0), static signs) + bias and write float4.
// Slice sl = (i*2+oc)*4+gch, layout [64 b][128 n] bf16; n = (o&31)*4+x.
// ---------------------------------------------------------------------------
__global__ __launch_bounds__(256)
void kan_tail(const unsigned short* __restrict__ part,
              const float* __restrict__ xg,
              const float* __restrict__ sw,
              const float* __restrict__ sb,
              float* __restrict__ out)
{
    __shared__ float4 sums[16][16];

    const int t     = threadIdx.x;
    const int bid   = blockIdx.x;            // 0..255
    const int pairL = t & 15;
    const int rgrp  = t >> 4;
    const int pairG = bid * 16 + pairL;
    const int b     = pairG >> 6, o = pairG & 63;
    const int oc    = o >> 5;

    float4 s4 = make_float4(0.f, 0.f, 0.f, 0.f);
    #pragma unroll 4
    for (int m = 0; m < 16; ++m) {
        const int idx = rgrp * 16 + m;       // (i, gch) pair
        const int ii  = idx >> 2, gg = idx & 3;
        const size_t sl = (size_t)((ii * 2 + oc) * 4 + gg);
        const u16x4 v = *reinterpret_cast<const u16x4*>(
            part + sl * (BB * 128) + b * 128 + (o & 31) * 4);
        s4.x += bfu2f(v[0]); s4.y += bfu2f(v[1]);
        s4.z += bfu2f(v[2]); s4.w += bfu2f(v[3]);
    }
    sums[pairL][rgrp] = s4;
    __syncthreads();

    if (t < 16) {
        const int pg = bid * 16 + t;
        const int bb = pg >> 6, oo = pg & 63;

        float o0 = 0.f, o1 = 0.f, o2 = 0.f, o3 = 0.f;
        #pragma unroll
        for (int r = 0; r < 16; ++r) {
            const float4 v = sums[t][r];
            o0 += v.x; o1 += v.y; o2 += v.z; o3 += v.w;
        }

        const float4* xg4 = reinterpret_cast<const float4*>(xg);
        const float4* sw4 = reinterpret_cast<const float4*>(sw);
        const float4* sb4 = reinterpret_cast<const float4*>(sb);
        #pragma unroll 4
        for (int i = 0; i < II; ++i) {
            const float4 xvv = xg4[bb * II + i];
            const float4 swv = sw4[i * OO + oo];
            const float4 sbv = sb4[i * OO + oo];
            const float s0 = xvv.x / (1.f + __expf(-xvv.x));
            const float s1 = xvv.y / (1.f + __expf(-xvv.y));
            const float s2 = xvv.z / (1.f + __expf(-xvv.z));
            const float s3 = xvv.w / (1.f + __expf(-xvv.w));
            o0 += swv.x * s0 + swv.y * s1 + swv.z * s2 - swv.w * s3 + sbv.x;
            o1 += swv.x * s1 + swv.y * s0 - swv.z * s3 + swv.w * s2 + sbv.y;
            o2 += swv.x * s2 + swv.y * s3 + swv.z * s0 - swv.w * s1 + sbv.z;
            o3 += swv.x * s3 + swv.y * s2 - swv.z * s1 + swv.w * s0 + sbv.w;
        }
        reinterpret_cast<float4*>(out)[pg] = make_float4(o0, o1, o2, o3);
    }
}

// ---------------------------------------------------------------------------
// Fallback-only final kernel (atomic path): main sums already in out
// ---------------------------------------------------------------------------
__global__ void kan_out(const float* __restrict__ xg,
                        const float* __restrict__ sw,
                        const float* __restrict__ sb,
                        float* __restrict__ out)
{
    const int t = blockIdx.x * 256 + threadIdx.x;    // (b,o)
    const int b = t >> 6, o = t & 63;

    const float4 v = reinterpret_cast<const float4*>(out)[t];
    float o0 = v.x, o1 = v.y, o2 = v.z, o3 = v.w;

    const float4* xg4 = reinterpret_cast<const float4*>(xg);
    const float4* sw4 = reinterpret_cast<const float4*>(sw);
    const float4* sb4 = reinterpret_cast<const float4*>(sb);
    #pragma unroll 4
    for (int i = 0; i < II; ++i) {
        const float4 xvv = xg4[b * II + i];
        const float4 swv = sw4[i * OO + o];
        const float4 sbv = sb4[i * OO + o];
        const float s0 = xvv.x / (1.f + __expf(-xvv.x));
        const float s1 = xvv.y / (1.f + __expf(-xvv.y));
        const float s2 = xvv.z / (1.f + __expf(-xvv.z));
        const float s3 = xvv.w / (1.f + __expf(-xvv.w));
        o0 += swv.x * s0 + swv.y * s1 + swv.z * s2 - swv.w * s3 + sbv.x;
        o1 += swv.x * s1 + swv.y * s0 - swv.z * s3 + swv.w * s2 + sbv.y;
        o2 += swv.x * s2 + swv.y * s3 + swv.z * s0 - swv.w * s1 + sbv.z;
        o3 += swv.x * s3 + swv.y * s2 - swv.z * s1 + swv.w * s0 + sbv.w;
    }
    reinterpret_cast<float4*>(out)[t] = make_float4(o0, o1, o2, o3);
}

// ---------------------------------------------------------------------------
extern "C" void kernel_launch(void* const* d_in, const int* in_sizes, int n_in,
                              void* d_out, int out_size, void* d_ws, size_t ws_size,
                              hipStream_t stream)
{
    const float* x   = (const float*)d_in[0];
    const float* grd = (const float*)d_in[1];
    const float* w   = (const float*)d_in[2];
    const float* sw  = (const float*)d_in[3];
    const float* sb  = (const float*)d_in[4];
    float* out = (float*)d_out;

    const size_t need = (size_t)NSL * (BB * 128) * 2;   // 8 MB

    if (ws_size >= need) {
        unsigned short* ws = (unsigned short*)d_ws;
        kan_main<<<dim3(64, 2, 4), 512, 0, stream>>>(x, grd, w, ws, nullptr, 0);
        kan_tail<<<256, 256, 0, stream>>>(ws, x, sw, sb, out);
    } else {
        hipMemsetAsync(d_out, 0, (size_t)out_size * sizeof(float), stream);
        kan_main<<<dim3(64, 2, 4), 512, 0, stream>>>(x, grd, w, nullptr, out, 1);
        kan_out<<<16, 256, 0, stream>>>(x, sw, sb, out);
    }
}